// Round 19
// baseline (664.513 us; speedup 1.0000x reference)
//
#include <hip/hip_runtime.h>

constexpr int B_ = 64, N_ = 500, E_ = 16000, L_ = 64, G_ = 64, F_ = 8, H_ = 128;
constexpr int GL_ = 4096;     // G*L
constexpr int NP_ = 512;      // n padded
constexpr int KS_ = 4;        // K-split planes per chunk
constexpr int ACC_ELEMS = B_ * N_ * G_;               // 2,048,000

using bf16x8  = __attribute__((ext_vector_type(8))) short;
using f32x4   = __attribute__((ext_vector_type(4))) float;
using ushort8 = __attribute__((ext_vector_type(8))) unsigned short;

#define MFMA16(a, b, c) __builtin_amdgcn_mfma_f32_16x16x32_bf16((a), (b), (c), 0, 0, 0)

static __device__ __forceinline__ unsigned short f2bf(float f) {
    union { float f; unsigned u; } v; v.f = f;
    unsigned r = v.u + 0x7fffu + ((v.u >> 16) & 1u);
    return (unsigned short)(r >> 16);
}
static __device__ __forceinline__ float bf2f(unsigned short s) {
    union { float f; unsigned u; } v; v.u = ((unsigned)s) << 16;
    return v.f;
}

// ---- direct-load 64x128 GEMM (k_accd pattern): no LDS/barriers in loop -----
// C[M][ldc] = A[M][K] @ Bm[4096][K]^T ; lda == ldb == K (k-contiguous rows).
// Grid mapping: bid = xcd + 8*idx; same XCD walks m with fixed n-panel.
static __device__ __forceinline__ void gemm_direct(
    const unsigned short* __restrict__ A,
    const unsigned short* __restrict__ Bm,
    int K, int Mt,
    unsigned short* __restrict__ C, int ldc,
    const float* __restrict__ bias,
    unsigned short* __restrict__ CsRaw)
{
    const int bid = blockIdx.x;
    const int xcd = bid & 7, idx = bid >> 3;         // idx 0..Mt*4-1
    const int m0 = (idx % Mt) * 64;
    const int n0 = (xcd + 8 * (idx / Mt)) * 128;

    const int tid = threadIdx.x, lane = tid & 63, wid = tid >> 6;
    const int wm = wid >> 1, wn = wid & 1;
    const int fr = lane & 15, fq = lane >> 4;

    const f32x4 fz = {0.f, 0.f, 0.f, 0.f};
    f32x4 acc[2][4] = {{fz, fz, fz, fz}, {fz, fz, fz, fz}};

    const unsigned short* Ap = &A[(size_t)(m0 + wm * 32 + fr) * K];
    const unsigned short* Bp = &Bm[(size_t)(n0 + wn * 64 + fr) * K];

    for (int kk = 0; kk < K; kk += 64) {
        #pragma unroll
        for (int ks = 0; ks < 2; ++ks) {
            const int ko = kk + ks * 32 + fq * 8;
            bf16x8 af[2], bf[4];
            #pragma unroll
            for (int i = 0; i < 2; ++i)
                af[i] = *(const bf16x8*)&Ap[(size_t)(i * 16) * K + ko];
            #pragma unroll
            for (int j = 0; j < 4; ++j)
                bf[j] = *(const bf16x8*)&Bp[(size_t)(j * 16) * K + ko];
            #pragma unroll
            for (int i = 0; i < 2; ++i)
                #pragma unroll
                for (int j = 0; j < 4; ++j)
                    acc[i][j] = MFMA16(af[i], bf[j], acc[i][j]);
        }
    }

    // epilogue: swizzled LDS repack -> coalesced 16B stores
    auto Cs = (unsigned short(*)[128])CsRaw;
    #pragma unroll
    for (int i = 0; i < 2; ++i)
        #pragma unroll
        for (int j = 0; j < 4; ++j) {
            const float bv = bias ? bias[n0 + wn * 64 + j * 16 + fr] : 0.f;
            #pragma unroll
            for (int r = 0; r < 4; ++r)
                Cs[wm * 32 + i * 16 + fq * 4 + r]
                  [(wn * 64 + j * 16 + fr) ^ (fq << 3)] =
                    f2bf(acc[i][j][r] + bv);
        }
    __syncthreads();
    const int r2 = tid >> 4, o2 = (tid & 15) * 8;
    #pragma unroll
    for (int i = 0; i < 4; ++i) {
        const int row = i * 16 + r2;
        const int o2s = o2 ^ (((row >> 2) & 3) << 3);
        *(uint4*)&C[(size_t)(m0 + row) * ldc + n0 + o2] = *(const uint4*)&Cs[row][o2s];
    }
}

// ---- merged dispatch: y==0 -> K-gen (K=128,+bias), y==1 -> t-gemm (K=512) --
__global__ __launch_bounds__(256)
void gemm_pair(const unsigned short* __restrict__ A0,
               const unsigned short* __restrict__ B0, int K0,
               unsigned short* __restrict__ C0, const float* __restrict__ bias0,
               const unsigned short* __restrict__ A1,
               const unsigned short* __restrict__ B1, int K1,
               unsigned short* __restrict__ C1, int Mt)
{
    __shared__ __align__(16) unsigned short Cs[64 * 128];   // 16 KB
    if (blockIdx.y == 0)
        gemm_direct(A0, B0, K0, Mt, C0, GL_, bias0, Cs);
    else
        gemm_direct(A1, B1, K1, Mt, C1, GL_, nullptr, Cs);
}

// ---- k_y8: per block 8 edges; wave w computes y[e0+w] = t[e]@K[e]^T --------
__global__ __launch_bounds__(512)
void k_y8(unsigned short* tc, const unsigned short* __restrict__ Kc)
{
    const int e0 = blockIdx.x * 8;
    const int tid = threadIdx.x, lane = tid & 63, w = tid >> 6;
    const int e = e0 + w;
    const int fr = lane & 15, fq = lane >> 4;
    const unsigned short* A  = &tc[(size_t)e * GL_];
    const unsigned short* Bp = &Kc[(size_t)e * GL_];
    const f32x4 fz = {0.f, 0.f, 0.f, 0.f};
    f32x4 acc[4][4] = {{fz, fz, fz, fz}, {fz, fz, fz, fz},
                       {fz, fz, fz, fz}, {fz, fz, fz, fz}};
    #pragma unroll
    for (int ks = 0; ks < 2; ++ks) {
        bf16x8 af[4], bf[4];
        #pragma unroll
        for (int i = 0; i < 4; ++i)
            af[i] = *(const bf16x8*)&A[(i * 16 + fr) * 64 + ks * 32 + fq * 8];
        #pragma unroll
        for (int j = 0; j < 4; ++j)
            bf[j] = *(const bf16x8*)&Bp[(j * 16 + fr) * 64 + ks * 32 + fq * 8];
        #pragma unroll
        for (int i = 0; i < 4; ++i)
            #pragma unroll
            for (int j = 0; j < 4; ++j)
                acc[i][j] = MFMA16(af[i], bf[j], acc[i][j]);
    }
    __shared__ unsigned short y8[GL_ * 8];   // 64KB, [bg][8]
    #pragma unroll
    for (int i = 0; i < 4; ++i)
        #pragma unroll
        for (int j = 0; j < 4; ++j)
            #pragma unroll
            for (int r = 0; r < 4; ++r) {
                const int bg = (i * 16 + fq * 4 + r) * 64 + j * 16 + fr;
                y8[bg * 8 + w] = f2bf(acc[i][j][r]);
            }
    __syncthreads();
    unsigned short* dst = tc + (size_t)e0 * GL_;
    #pragma unroll
    for (int p = 0; p < 8; ++p) {
        const int o = (p * 512 + tid) * 8;
        *(uint4*)&dst[o] = *(const uint4*)&y8[o];
    }
}

// ---- k_accd: planes[pbase+ky] = incB8 @ y8^T, 64x128 tiles, direct loads ---
__global__ __launch_bounds__(256)
void k_accd(const unsigned short* __restrict__ Ae,   // incB8 + e_off*NP_
            const unsigned short* __restrict__ y8,   // chunk tc base
            unsigned short* __restrict__ planesB, int pbase, int K)
{
    const int xcd = blockIdx.x & 7, grp = blockIdx.x >> 3;   // grp 0..31
    const int m0 = (grp & 7) * 64;
    const int n0 = (xcd + 8 * (grp >> 3)) * 128;
    const int KSY = gridDim.y;
    const int kl = ((K / KSY) / 64) * 64;
    const int kbeg = blockIdx.y * kl;
    const int kend = ((int)blockIdx.y == KSY - 1) ? K : kbeg + kl;

    const int lane = threadIdx.x & 63, wid = threadIdx.x >> 6;
    const int wm = wid >> 1, wn = wid & 1;
    const int fr = lane & 15, fq = lane >> 4;

    const f32x4 fz = {0.f, 0.f, 0.f, 0.f};
    f32x4 acc[2][4] = {{fz, fz, fz, fz}, {fz, fz, fz, fz}};

    for (int kk = kbeg; kk < kend; kk += 64) {
        #pragma unroll
        for (int ks = 0; ks < 2; ++ks) {
            const int e8 = kk + ks * 32 + fq * 8;
            const size_t eb = (size_t)(e8 >> 3);
            bf16x8 af[2], bf[4];
            #pragma unroll
            for (int i = 0; i < 2; ++i)
                af[i] = *(const bf16x8*)&Ae[(eb * NP_ + m0 + wm * 32 + i * 16 + fr) * 8];
            #pragma unroll
            for (int j = 0; j < 4; ++j)
                bf[j] = *(const bf16x8*)&y8[eb * GL_ * 8 + (n0 + wn * 64 + j * 16 + fr) * 8];
            #pragma unroll
            for (int i = 0; i < 2; ++i)
                #pragma unroll
                for (int j = 0; j < 4; ++j)
                    acc[i][j] = MFMA16(af[i], bf[j], acc[i][j]);
        }
    }

    unsigned short* pl = planesB + (size_t)(pbase + blockIdx.y) * ACC_ELEMS;
    #pragma unroll
    for (int i = 0; i < 2; ++i)
        #pragma unroll
        for (int j = 0; j < 4; ++j) {
            const int col = n0 + wn * 64 + j * 16 + fr;
            const int b = col >> 6, g = col & 63;
            #pragma unroll
            for (int r = 0; r < 4; ++r) {
                const int n = m0 + wm * 32 + i * 16 + fq * 4 + r;
                if (n < N_)
                    pl[((size_t)b * N_ + n) * G_ + g] = f2bf(acc[i][j][r]);
            }
        }
}

// ======================= merged prologue (1 dispatch) =======================
constexpr int PREP_CVT = 2000, PREP_XT = 2512, PREP_W2 = 2640, PREP_NB = 10640;

__global__ __launch_bounds__(256)
void k_prep(const float* __restrict__ x, const float* __restrict__ inc,
            const float* __restrict__ ef, const float* __restrict__ W1,
            const float* __restrict__ b1, const float* __restrict__ W2,
            unsigned short* __restrict__ incT, unsigned short* __restrict__ incB8,
            unsigned short* __restrict__ xT, unsigned short* __restrict__ W2T,
            unsigned short* __restrict__ h)
{
    __shared__ __align__(16) char smraw[64 * 65 * 4];
    const int q = blockIdx.x;
    const int tid = threadIdx.x;

    if (q < PREP_CVT) {
        auto sm = (unsigned short(*)[80])smraw;
        const int e0 = (q % 250) * 64, n0 = (q / 250) * 64;
        const int cl = tid & 63;
        for (int rr = tid >> 6; rr < 64; rr += 4) {
            const int n = n0 + rr;
            sm[cl][rr] = (n < N_) ? f2bf(inc[(size_t)n * E_ + e0 + cl]) : (unsigned short)0;
        }
        __syncthreads();
        {
            const int cw = tid >> 2, j0 = (tid & 3) * 16;
            *(ushort8*)&incT[(size_t)(e0 + cw) * NP_ + n0 + j0]     = *(const ushort8*)&sm[cw][j0];
            *(ushort8*)&incT[(size_t)(e0 + cw) * NP_ + n0 + j0 + 8] = *(const ushort8*)&sm[cw][j0 + 8];
        }
        {
            const int eb = tid >> 5, idx = tid & 31;
            #pragma unroll
            for (int k = 0; k < 2; ++k) {
                const int row = idx * 2 + k;
                unsigned short tmp[8];
                #pragma unroll
                for (int p = 0; p < 8; ++p) tmp[p] = sm[eb * 8 + p][row];
                *(ushort8*)&incB8[((size_t)((e0 >> 3) + eb) * NP_ + n0 + row) * 8] =
                    *(const ushort8*)&tmp[0];
            }
        }
    } else if (q < PREP_W2) {
        auto sm = (float(*)[65])smraw;
        const float* in; unsigned short* out;
        int R, C, Rp, c0, r0;
        if (q < PREP_XT) {
            const int t = q - PREP_CVT, z = t >> 3, by = t & 7;
            in = x + (size_t)z * N_ * L_; out = xT + (size_t)z * L_ * NP_;
            R = N_; C = L_; Rp = NP_; c0 = 0; r0 = by * 64;
        } else {
            const int t = q - PREP_XT;
            in = W2; out = W2T;
            R = H_; C = GL_; Rp = H_; c0 = (t & 63) * 64; r0 = (t >> 6) * 64;
        }
        const int cl = tid & 63;
        for (int rr = tid >> 6; rr < 64; rr += 4) {
            const int r = r0 + rr;
            sm[cl][rr] = (r < R) ? in[(size_t)r * C + c0 + cl] : 0.f;
        }
        __syncthreads();
        const int cw = tid >> 2, j0 = (tid & 3) * 16;
        unsigned short tmp[16];
        #pragma unroll
        for (int j = 0; j < 16; ++j) tmp[j] = f2bf(sm[cw][j0 + j]);
        *(ushort8*)&out[(size_t)(c0 + cw) * Rp + r0 + j0]     = *(ushort8*)&tmp[0];
        *(ushort8*)&out[(size_t)(c0 + cw) * Rp + r0 + j0 + 8] = *(ushort8*)&tmp[8];
    } else {
        const int idx = (q - PREP_W2) * 256 + tid;
        const int e = idx >> 7, hh = idx & 127;
        float v = b1[hh];
        const float* efp = &ef[(size_t)e * F_];
        #pragma unroll
        for (int f = 0; f < F_; ++f) v += efp[f] * W1[f * H_ + hh];
        h[idx] = f2bf(fmaxf(v, 0.f));
    }
}

// ---- final: out = relu(sum_p bf16 planes[p] + bgc), single d_out write -----
__global__ __launch_bounds__(256)
void k_final(const unsigned short* __restrict__ planesB, int P,
             const float* __restrict__ bgc, float* __restrict__ out)
{
    const int i = (blockIdx.x * 256 + threadIdx.x) * 8;
    if (i >= ACC_ELEMS) return;
    float s[8];
    #pragma unroll
    for (int j = 0; j < 8; ++j) s[j] = bgc[(i + j) & 63];
    for (int p = 0; p < P; ++p) {
        const ushort8 v = *(const ushort8*)&planesB[(size_t)p * ACC_ELEMS + i];
        #pragma unroll
        for (int j = 0; j < 8; ++j) s[j] += bf2f((unsigned short)v[j]);
    }
    float4 o0, o1;
    o0.x = fmaxf(s[0], 0.f); o0.y = fmaxf(s[1], 0.f);
    o0.z = fmaxf(s[2], 0.f); o0.w = fmaxf(s[3], 0.f);
    o1.x = fmaxf(s[4], 0.f); o1.y = fmaxf(s[5], 0.f);
    o1.z = fmaxf(s[6], 0.f); o1.w = fmaxf(s[7], 0.f);
    *(float4*)&out[i]     = o0;
    *(float4*)&out[i + 4] = o1;
}

extern "C" void kernel_launch(void* const* d_in, const int* in_sizes, int n_in,
                              void* d_out, int out_size, void* d_ws, size_t ws_size,
                              hipStream_t stream) {
    const float* x   = (const float*)d_in[0];
    const float* inc = (const float*)d_in[1];
    const float* ef  = (const float*)d_in[2];
    const float* W1  = (const float*)d_in[3];
    const float* b1  = (const float*)d_in[4];
    const float* W2  = (const float*)d_in[5];
    const float* b2  = (const float*)d_in[6];
    const float* bgc = (const float*)d_in[7];
    float* out = (float*)d_out;

    const size_t persistU16 = (size_t)NP_ * E_      // incB8
                            + (size_t)E_ * NP_      // incT
                            + (size_t)B_ * L_ * NP_ // xT
                            + (size_t)E_ * H_       // h
                            + (size_t)GL_ * H_;     // W2T
    const size_t persistBytes = persistU16 * 2;     // ~41.9 MB

    int nc = 1, Ec = E_;
    for (; nc <= 16; ++nc) {
        Ec = ((E_ + nc - 1) / nc + 127) / 128 * 128;
        const size_t need = persistBytes
                          + (size_t)nc * KS_ * ACC_ELEMS * 2     // bf16 planes
                          + 2 * (size_t)Ec * GL_ * 2;            // K + t chunk
        if (need <= ws_size) break;
    }
    if (nc > 16) { nc = 16; Ec = 1024; }

    unsigned short* planesB = (unsigned short*)d_ws;
    unsigned short* incB8 = planesB + (size_t)nc * KS_ * ACC_ELEMS;
    unsigned short* incT = incB8 + (size_t)NP_ * E_;
    unsigned short* xT   = incT + (size_t)E_ * NP_;
    unsigned short* h    = xT   + (size_t)B_ * L_ * NP_;
    unsigned short* W2T  = h    + (size_t)E_ * H_;
    unsigned short* Kc   = W2T  + (size_t)GL_ * H_;    // [Ec][4096]
    unsigned short* tc   = Kc   + (size_t)Ec * GL_;    // [Ec][4096]; later y8

    k_prep<<<dim3(PREP_NB), 256, 0, stream>>>(x, inc, ef, W1, b1, W2,
                                              incT, incB8, xT, W2T, h);

    int cidx = 0;
    for (int e_off = 0; e_off < E_; e_off += Ec, ++cidx) {
        const int ec = (E_ - e_off) < Ec ? (E_ - e_off) : Ec;   // multiple of 128
        const int Mt = ec / 64;
        gemm_pair<<<dim3(Mt * 32, 2), 256, 0, stream>>>(
            h + (size_t)e_off * H_, W2T, H_, Kc, b2,
            incT + (size_t)e_off * NP_, xT, NP_, tc, Mt);
        k_y8<<<dim3(ec / 8), 512, 0, stream>>>(tc, Kc);             // y8 over t
        k_accd<<<dim3(256, KS_), 256, 0, stream>>>(
            incB8 + (size_t)e_off * NP_, tc, planesB, cidx * KS_, ec);
    }

    k_final<<<dim3(ACC_ELEMS / 2048), 256, 0, stream>>>(planesB, nc * KS_, bgc, out);
}

// Round 20
// 352.115 us; speedup vs baseline: 1.8872x; 1.8872x over previous
//
#include <hip/hip_runtime.h>

constexpr int B_ = 64, N_ = 500, E_ = 16000, L_ = 64, G_ = 64, F_ = 8, H_ = 128;
constexpr int GL_ = 4096;     // G*L
constexpr int NP_ = 512;      // n padded
constexpr int KS_ = 4;        // K-split planes per chunk
constexpr int ACC_ELEMS = B_ * N_ * G_;               // 2,048,000

using bf16x8  = __attribute__((ext_vector_type(8))) short;
using f32x4   = __attribute__((ext_vector_type(4))) float;
using ushort8 = __attribute__((ext_vector_type(8))) unsigned short;

#define MFMA16(a, b, c) __builtin_amdgcn_mfma_f32_16x16x32_bf16((a), (b), (c), 0, 0, 0)

typedef __attribute__((address_space(3))) unsigned int       lds_u32;
typedef const __attribute__((address_space(1))) unsigned int glb_u32;

static __device__ __forceinline__ unsigned short f2bf(float f) {
    union { float f; unsigned u; } v; v.f = f;
    unsigned r = v.u + 0x7fffu + ((v.u >> 16) & 1u);
    return (unsigned short)(r >> 16);
}
static __device__ __forceinline__ float bf2f(unsigned short s) {
    union { float f; unsigned u; } v; v.u = ((unsigned)s) << 16;
    return v.f;
}

// stage 128x32 bf16 tile (8 KB = 512 x 16B chunks) global->LDS, pre-swizzled
// source (rule #21): LDS chunk (row,c) holds global chunk (row, c^((row>>1)&3)).
static __device__ __forceinline__ void stage32(
    const unsigned short* __restrict__ g, int ld, int r0, int kk,
    unsigned short* lds, int tid)
{
    #pragma unroll
    for (int c = 0; c < 2; ++c) {
        const int ch  = tid + c * 256;              // 0..511
        const int row = ch >> 2;
        const int csw = (ch & 3) ^ ((row >> 1) & 3);
        __builtin_amdgcn_global_load_lds(
            (glb_u32*)(g + (size_t)(r0 + row) * ld + kk + csw * 8),
            (lds_u32*)(lds + (size_t)ch * 8), 16, 0, 0);
    }
}

// ---- 128x128 GEMM body: BK=32, 3-buffer, depth-2, ONE barrier per K-step ---
static __device__ __forceinline__ void gemm_body(
    const unsigned short* __restrict__ A, int lda,
    const unsigned short* __restrict__ Bm, int ldb,
    int K, int nN,
    unsigned short* __restrict__ C, int ldc,
    const float* __restrict__ bias)
{
    const int nwg = gridDim.x;
    const int bid = blockIdx.x;
    const int swz = (nwg & 7) ? bid : ((bid & 7) * (nwg >> 3) + (bid >> 3));
    const int m0 = (swz / nN) * 128, n0 = (swz % nN) * 128;

    const int tid  = threadIdx.x;
    const int lane = tid & 63, wid = tid >> 6;
    const int wm = wid >> 1, wn = wid & 1;
    const int fr = lane & 15, fq = lane >> 4;

    __shared__ __align__(16) unsigned short smem[3 * 8192];   // 48 KB: 3x(A+B)

    const f32x4 fz = {0.f, 0.f, 0.f, 0.f};
    f32x4 acc[4][4] = {{fz, fz, fz, fz}, {fz, fz, fz, fz},
                       {fz, fz, fz, fz}, {fz, fz, fz, fz}};

    const int rowA[4] = {wm * 64 + 0 * 16 + fr, wm * 64 + 1 * 16 + fr,
                         wm * 64 + 2 * 16 + fr, wm * 64 + 3 * 16 + fr};
    const int rowB[4] = {wn * 64 + 0 * 16 + fr, wn * 64 + 1 * 16 + fr,
                         wn * 64 + 2 * 16 + fr, wn * 64 + 3 * 16 + fr};
    int cA[4], cB[4];
    #pragma unroll
    for (int i = 0; i < 4; ++i) {
        cA[i] = (fq ^ ((rowA[i] >> 1) & 3)) * 8;
        cB[i] = (fq ^ ((rowB[i] >> 1) & 3)) * 8;
    }

    const int nk = K / 32;
    stage32(A, lda, m0, 0, smem, tid);                 // tile 0 -> buf 0
    stage32(Bm, ldb, n0, 0, smem + 4096, tid);
    stage32(A, lda, m0, 32, smem + 8192, tid);         // tile 1 -> buf 1
    stage32(Bm, ldb, n0, 32, smem + 8192 + 4096, tid);

    int cur = 0;
    for (int kt = 0; kt < nk; ++kt) {
        if (kt + 1 < nk) {
            asm volatile("s_waitcnt vmcnt(4)" ::: "memory");
        } else {
            asm volatile("s_waitcnt vmcnt(0)" ::: "memory");
        }
        __builtin_amdgcn_s_barrier();
        __builtin_amdgcn_sched_barrier(0);
        if (kt + 2 < nk) {
            int nxt = cur + 2; if (nxt >= 3) nxt -= 3;
            unsigned short* const An = smem + nxt * 8192;
            stage32(A, lda, m0, (kt + 2) * 32, An, tid);
            stage32(Bm, ldb, n0, (kt + 2) * 32, An + 4096, tid);
        }
        unsigned short* const As = smem + cur * 8192;
        unsigned short* const Bs = As + 4096;
        {
            bf16x8 af[4], bf[4];
            #pragma unroll
            for (int i = 0; i < 4; ++i)
                af[i] = *(const bf16x8*)&As[rowA[i] * 32 + cA[i]];
            #pragma unroll
            for (int j = 0; j < 4; ++j)
                bf[j] = *(const bf16x8*)&Bs[rowB[j] * 32 + cB[j]];
            #pragma unroll
            for (int i = 0; i < 4; ++i)
                #pragma unroll
                for (int j = 0; j < 4; ++j)
                    acc[i][j] = MFMA16(af[i], bf[j], acc[i][j]);
        }
        __builtin_amdgcn_sched_barrier(0);
        cur = (cur + 1 == 3) ? 0 : cur + 1;
    }

    __syncthreads();                           // loop reads done before Cs reuse
    auto Cs = (unsigned short(*)[128])smem;    // 32 KB of the 48 KB
    #pragma unroll
    for (int i = 0; i < 4; ++i)
        #pragma unroll
        for (int j = 0; j < 4; ++j) {
            const float bv = bias ? bias[n0 + wn * 64 + j * 16 + fr] : 0.f;
            #pragma unroll
            for (int r = 0; r < 4; ++r)
                Cs[wm * 64 + i * 16 + fq * 4 + r]
                  [(wn * 64 + j * 16 + fr) ^ (fq << 3)] =      // bank swizzle
                    f2bf(acc[i][j][r] + bv);
        }
    __syncthreads();
    const int r2 = tid >> 4, o2 = (tid & 15) * 8;
    #pragma unroll
    for (int i = 0; i < 8; ++i) {
        const int row = i * 16 + r2;
        const int o2s = o2 ^ (((row >> 2) & 3) << 3);          // undo swizzle
        *(uint4*)&C[(size_t)(m0 + row) * ldc + n0 + o2] = *(const uint4*)&Cs[row][o2s];
    }
}

// ---- merged dispatch: y==0 -> K-gen (bias), y==1 -> t-gemm -----------------
__global__ __launch_bounds__(256)
void gemm_pair(const unsigned short* __restrict__ A0, int lda0,
               const unsigned short* __restrict__ B0, int ldb0, int K0,
               unsigned short* __restrict__ C0, const float* __restrict__ bias0,
               const unsigned short* __restrict__ A1, int lda1,
               const unsigned short* __restrict__ B1, int ldb1, int K1,
               unsigned short* __restrict__ C1, int nN)
{
    if (blockIdx.y == 0)
        gemm_body(A0, lda0, B0, ldb0, K0, nN, C0, GL_, bias0);
    else
        gemm_body(A1, lda1, B1, ldb1, K1, nN, C1, GL_, nullptr);
}

// ---- k_y8: per block 8 edges; wave w computes y[e0+w] = t[e]@K[e]^T --------
__global__ __launch_bounds__(512)
void k_y8(unsigned short* tc, const unsigned short* __restrict__ Kc)
{
    const int e0 = blockIdx.x * 8;
    const int tid = threadIdx.x, lane = tid & 63, w = tid >> 6;
    const int e = e0 + w;
    const int fr = lane & 15, fq = lane >> 4;
    const unsigned short* A  = &tc[(size_t)e * GL_];
    const unsigned short* Bp = &Kc[(size_t)e * GL_];
    const f32x4 fz = {0.f, 0.f, 0.f, 0.f};
    f32x4 acc[4][4] = {{fz, fz, fz, fz}, {fz, fz, fz, fz},
                       {fz, fz, fz, fz}, {fz, fz, fz, fz}};
    #pragma unroll
    for (int ks = 0; ks < 2; ++ks) {
        bf16x8 af[4], bf[4];
        #pragma unroll
        for (int i = 0; i < 4; ++i)
            af[i] = *(const bf16x8*)&A[(i * 16 + fr) * 64 + ks * 32 + fq * 8];
        #pragma unroll
        for (int j = 0; j < 4; ++j)
            bf[j] = *(const bf16x8*)&Bp[(j * 16 + fr) * 64 + ks * 32 + fq * 8];
        #pragma unroll
        for (int i = 0; i < 4; ++i)
            #pragma unroll
            for (int j = 0; j < 4; ++j)
                acc[i][j] = MFMA16(af[i], bf[j], acc[i][j]);
    }
    __shared__ unsigned short y8[GL_ * 8];   // 64KB, [bg][8]
    #pragma unroll
    for (int i = 0; i < 4; ++i)
        #pragma unroll
        for (int j = 0; j < 4; ++j)
            #pragma unroll
            for (int r = 0; r < 4; ++r) {
                const int bg = (i * 16 + fq * 4 + r) * 64 + j * 16 + fr;
                y8[bg * 8 + w] = f2bf(acc[i][j][r]);
            }
    __syncthreads();
    unsigned short* dst = tc + (size_t)e0 * GL_;
    #pragma unroll
    for (int p = 0; p < 8; ++p) {
        const int o = (p * 512 + tid) * 8;
        *(uint4*)&dst[o] = *(const uint4*)&y8[o];
    }
}

// ---- k_accd: planes[pbase+ky] = incB8 @ y8^T, 64x128 tiles, direct loads ---
__global__ __launch_bounds__(256)
void k_accd(const unsigned short* __restrict__ Ae,   // incB8 + e_off*NP_
            const unsigned short* __restrict__ y8,   // chunk tc base
            unsigned short* __restrict__ planesB, int pbase, int K)
{
    const int xcd = blockIdx.x & 7, grp = blockIdx.x >> 3;   // grp 0..31
    const int m0 = (grp & 7) * 64;
    const int n0 = (xcd + 8 * (grp >> 3)) * 128;
    const int KSY = gridDim.y;
    const int kl = ((K / KSY) / 64) * 64;
    const int kbeg = blockIdx.y * kl;
    const int kend = ((int)blockIdx.y == KSY - 1) ? K : kbeg + kl;

    const int lane = threadIdx.x & 63, wid = threadIdx.x >> 6;
    const int wm = wid >> 1, wn = wid & 1;
    const int fr = lane & 15, fq = lane >> 4;

    const f32x4 fz = {0.f, 0.f, 0.f, 0.f};
    f32x4 acc[2][4] = {{fz, fz, fz, fz}, {fz, fz, fz, fz}};

    for (int kk = kbeg; kk < kend; kk += 64) {
        #pragma unroll
        for (int ks = 0; ks < 2; ++ks) {
            const int e8 = kk + ks * 32 + fq * 8;
            const size_t eb = (size_t)(e8 >> 3);
            bf16x8 af[2], bf[4];
            #pragma unroll
            for (int i = 0; i < 2; ++i)
                af[i] = *(const bf16x8*)&Ae[(eb * NP_ + m0 + wm * 32 + i * 16 + fr) * 8];
            #pragma unroll
            for (int j = 0; j < 4; ++j)
                bf[j] = *(const bf16x8*)&y8[eb * GL_ * 8 + (n0 + wn * 64 + j * 16 + fr) * 8];
            #pragma unroll
            for (int i = 0; i < 2; ++i)
                #pragma unroll
                for (int j = 0; j < 4; ++j)
                    acc[i][j] = MFMA16(af[i], bf[j], acc[i][j]);
        }
    }

    unsigned short* pl = planesB + (size_t)(pbase + blockIdx.y) * ACC_ELEMS;
    #pragma unroll
    for (int i = 0; i < 2; ++i)
        #pragma unroll
        for (int j = 0; j < 4; ++j) {
            const int col = n0 + wn * 64 + j * 16 + fr;
            const int b = col >> 6, g = col & 63;
            #pragma unroll
            for (int r = 0; r < 4; ++r) {
                const int n = m0 + wm * 32 + i * 16 + fq * 4 + r;
                if (n < N_)
                    pl[((size_t)b * N_ + n) * G_ + g] = f2bf(acc[i][j][r]);
            }
        }
}

// ======================= merged prologue (1 dispatch) =======================
constexpr int PREP_CVT = 2000, PREP_XT = 2512, PREP_W2 = 2640, PREP_NB = 10640;

__global__ __launch_bounds__(256)
void k_prep(const float* __restrict__ x, const float* __restrict__ inc,
            const float* __restrict__ ef, const float* __restrict__ W1,
            const float* __restrict__ b1, const float* __restrict__ W2,
            unsigned short* __restrict__ incT, unsigned short* __restrict__ incB8,
            unsigned short* __restrict__ xT, unsigned short* __restrict__ W2T,
            unsigned short* __restrict__ h)
{
    __shared__ __align__(16) char smraw[64 * 65 * 4];
    const int q = blockIdx.x;
    const int tid = threadIdx.x;

    if (q < PREP_CVT) {
        auto sm = (unsigned short(*)[80])smraw;
        const int e0 = (q % 250) * 64, n0 = (q / 250) * 64;
        const int cl = tid & 63;
        for (int rr = tid >> 6; rr < 64; rr += 4) {
            const int n = n0 + rr;
            sm[cl][rr] = (n < N_) ? f2bf(inc[(size_t)n * E_ + e0 + cl]) : (unsigned short)0;
        }
        __syncthreads();
        {
            const int cw = tid >> 2, j0 = (tid & 3) * 16;
            *(ushort8*)&incT[(size_t)(e0 + cw) * NP_ + n0 + j0]     = *(const ushort8*)&sm[cw][j0];
            *(ushort8*)&incT[(size_t)(e0 + cw) * NP_ + n0 + j0 + 8] = *(const ushort8*)&sm[cw][j0 + 8];
        }
        {
            const int eb = tid >> 5, idx = tid & 31;
            #pragma unroll
            for (int k = 0; k < 2; ++k) {
                const int row = idx * 2 + k;
                unsigned short tmp[8];
                #pragma unroll
                for (int p = 0; p < 8; ++p) tmp[p] = sm[eb * 8 + p][row];
                *(ushort8*)&incB8[((size_t)((e0 >> 3) + eb) * NP_ + n0 + row) * 8] =
                    *(const ushort8*)&tmp[0];
            }
        }
    } else if (q < PREP_W2) {
        auto sm = (float(*)[65])smraw;
        const float* in; unsigned short* out;
        int R, C, Rp, c0, r0;
        if (q < PREP_XT) {
            const int t = q - PREP_CVT, z = t >> 3, by = t & 7;
            in = x + (size_t)z * N_ * L_; out = xT + (size_t)z * L_ * NP_;
            R = N_; C = L_; Rp = NP_; c0 = 0; r0 = by * 64;
        } else {
            const int t = q - PREP_XT;
            in = W2; out = W2T;
            R = H_; C = GL_; Rp = H_; c0 = (t & 63) * 64; r0 = (t >> 6) * 64;
        }
        const int cl = tid & 63;
        for (int rr = tid >> 6; rr < 64; rr += 4) {
            const int r = r0 + rr;
            sm[cl][rr] = (r < R) ? in[(size_t)r * C + c0 + cl] : 0.f;
        }
        __syncthreads();
        const int cw = tid >> 2, j0 = (tid & 3) * 16;
        unsigned short tmp[16];
        #pragma unroll
        for (int j = 0; j < 16; ++j) tmp[j] = f2bf(sm[cw][j0 + j]);
        *(ushort8*)&out[(size_t)(c0 + cw) * Rp + r0 + j0]     = *(ushort8*)&tmp[0];
        *(ushort8*)&out[(size_t)(c0 + cw) * Rp + r0 + j0 + 8] = *(ushort8*)&tmp[8];
    } else {
        const int idx = (q - PREP_W2) * 256 + tid;
        const int e = idx >> 7, hh = idx & 127;
        float v = b1[hh];
        const float* efp = &ef[(size_t)e * F_];
        #pragma unroll
        for (int f = 0; f < F_; ++f) v += efp[f] * W1[f * H_ + hh];
        h[idx] = f2bf(fmaxf(v, 0.f));
    }
}

// ---- final: out = relu(sum_p bf16 planes[p] + bgc), single d_out write -----
__global__ __launch_bounds__(256)
void k_final(const unsigned short* __restrict__ planesB, int P,
             const float* __restrict__ bgc, float* __restrict__ out)
{
    const int i = (blockIdx.x * 256 + threadIdx.x) * 8;
    if (i >= ACC_ELEMS) return;
    float s[8];
    #pragma unroll
    for (int j = 0; j < 8; ++j) s[j] = bgc[(i + j) & 63];
    for (int p = 0; p < P; ++p) {
        const ushort8 v = *(const ushort8*)&planesB[(size_t)p * ACC_ELEMS + i];
        #pragma unroll
        for (int j = 0; j < 8; ++j) s[j] += bf2f((unsigned short)v[j]);
    }
    float4 o0, o1;
    o0.x = fmaxf(s[0], 0.f); o0.y = fmaxf(s[1], 0.f);
    o0.z = fmaxf(s[2], 0.f); o0.w = fmaxf(s[3], 0.f);
    o1.x = fmaxf(s[4], 0.f); o1.y = fmaxf(s[5], 0.f);
    o1.z = fmaxf(s[6], 0.f); o1.w = fmaxf(s[7], 0.f);
    *(float4*)&out[i]     = o0;
    *(float4*)&out[i + 4] = o1;
}

extern "C" void kernel_launch(void* const* d_in, const int* in_sizes, int n_in,
                              void* d_out, int out_size, void* d_ws, size_t ws_size,
                              hipStream_t stream) {
    const float* x   = (const float*)d_in[0];
    const float* inc = (const float*)d_in[1];
    const float* ef  = (const float*)d_in[2];
    const float* W1  = (const float*)d_in[3];
    const float* b1  = (const float*)d_in[4];
    const float* W2  = (const float*)d_in[5];
    const float* b2  = (const float*)d_in[6];
    const float* bgc = (const float*)d_in[7];
    float* out = (float*)d_out;

    const size_t persistU16 = (size_t)NP_ * E_      // incB8
                            + (size_t)E_ * NP_      // incT
                            + (size_t)B_ * L_ * NP_ // xT
                            + (size_t)E_ * H_       // h
                            + (size_t)GL_ * H_;     // W2T
    const size_t persistBytes = persistU16 * 2;     // ~41.9 MB

    int nc = 1, Ec = E_;
    for (; nc <= 16; ++nc) {
        Ec = ((E_ + nc - 1) / nc + 127) / 128 * 128;
        const size_t need = persistBytes
                          + (size_t)nc * KS_ * ACC_ELEMS * 2     // bf16 planes
                          + 2 * (size_t)Ec * GL_ * 2;            // K + t chunk
        if (need <= ws_size) break;
    }
    if (nc > 16) { nc = 16; Ec = 1024; }

    unsigned short* planesB = (unsigned short*)d_ws;
    unsigned short* incB8 = planesB + (size_t)nc * KS_ * ACC_ELEMS;
    unsigned short* incT = incB8 + (size_t)NP_ * E_;
    unsigned short* xT   = incT + (size_t)E_ * NP_;
    unsigned short* h    = xT   + (size_t)B_ * L_ * NP_;
    unsigned short* W2T  = h    + (size_t)E_ * H_;
    unsigned short* Kc   = W2T  + (size_t)GL_ * H_;    // [Ec][4096]
    unsigned short* tc   = Kc   + (size_t)Ec * GL_;    // [Ec][4096]; later y8

    k_prep<<<dim3(PREP_NB), 256, 0, stream>>>(x, inc, ef, W1, b1, W2,
                                              incT, incB8, xT, W2T, h);

    int cidx = 0;
    for (int e_off = 0; e_off < E_; e_off += Ec, ++cidx) {
        const int ec = (E_ - e_off) < Ec ? (E_ - e_off) : Ec;   // multiple of 128
        gemm_pair<<<dim3((ec / 128) * 32, 2), 256, 0, stream>>>(
            h + (size_t)e_off * H_, H_, W2T, H_, H_, Kc, b2,
            incT + (size_t)e_off * NP_, NP_, xT, NP_, NP_, tc, 32);
        k_y8<<<dim3(ec / 8), 512, 0, stream>>>(tc, Kc);             // y8 over t
        k_accd<<<dim3(256, KS_), 256, 0, stream>>>(
            incB8 + (size_t)e_off * NP_, tc, planesB, cidx * KS_, ec);
    }

    k_final<<<dim3(ACC_ELEMS / 2048), 256, 0, stream>>>(planesB, nc * KS_, bgc, out);
}

// Round 21
// 345.380 us; speedup vs baseline: 1.9240x; 1.0195x over previous
//
#include <hip/hip_runtime.h>

constexpr int B_ = 64, N_ = 500, E_ = 16000, L_ = 64, G_ = 64, F_ = 8, H_ = 128;
constexpr int GL_ = 4096;     // G*L
constexpr int NP_ = 512;      // n padded
constexpr int ACC_ELEMS = B_ * N_ * G_;               // 2,048,000

using bf16x8  = __attribute__((ext_vector_type(8))) short;
using f32x4   = __attribute__((ext_vector_type(4))) float;
using ushort8 = __attribute__((ext_vector_type(8))) unsigned short;

#define MFMA16(a, b, c) __builtin_amdgcn_mfma_f32_16x16x32_bf16((a), (b), (c), 0, 0, 0)

typedef __attribute__((address_space(3))) unsigned int       lds_u32;
typedef const __attribute__((address_space(1))) unsigned int glb_u32;

static __device__ __forceinline__ unsigned short f2bf(float f) {
    union { float f; unsigned u; } v; v.f = f;
    unsigned r = v.u + 0x7fffu + ((v.u >> 16) & 1u);
    return (unsigned short)(r >> 16);
}
static __device__ __forceinline__ float bf2f(unsigned short s) {
    union { float f; unsigned u; } v; v.u = ((unsigned)s) << 16;
    return v.f;
}

// stage 128x32 bf16 tile (8 KB = 512 x 16B chunks) global->LDS, pre-swizzled
// source (rule #21): LDS chunk (row,c) holds global chunk (row, c^((row>>1)&3)).
static __device__ __forceinline__ void stage32(
    const unsigned short* __restrict__ g, int ld, int r0, int kk,
    unsigned short* lds, int tid)
{
    #pragma unroll
    for (int c = 0; c < 2; ++c) {
        const int ch  = tid + c * 256;              // 0..511
        const int row = ch >> 2;
        const int csw = (ch & 3) ^ ((row >> 1) & 3);
        __builtin_amdgcn_global_load_lds(
            (glb_u32*)(g + (size_t)(r0 + row) * ld + kk + csw * 8),
            (lds_u32*)(lds + (size_t)ch * 8), 16, 0, 0);
    }
}

// ---- 128x128 GEMM body: BK=32, 3-buffer, depth-2, ONE barrier per K-step ---
static __device__ __forceinline__ void gemm_body(
    const unsigned short* __restrict__ A, int lda,
    const unsigned short* __restrict__ Bm, int ldb,
    int K, int nN,
    unsigned short* __restrict__ C, int ldc,
    const float* __restrict__ bias)
{
    const int nwg = gridDim.x;
    const int bid = blockIdx.x;
    const int swz = (nwg & 7) ? bid : ((bid & 7) * (nwg >> 3) + (bid >> 3));
    const int m0 = (swz / nN) * 128, n0 = (swz % nN) * 128;

    const int tid  = threadIdx.x;
    const int lane = tid & 63, wid = tid >> 6;
    const int wm = wid >> 1, wn = wid & 1;
    const int fr = lane & 15, fq = lane >> 4;

    __shared__ __align__(16) unsigned short smem[3 * 8192];   // 48 KB: 3x(A+B)

    const f32x4 fz = {0.f, 0.f, 0.f, 0.f};
    f32x4 acc[4][4] = {{fz, fz, fz, fz}, {fz, fz, fz, fz},
                       {fz, fz, fz, fz}, {fz, fz, fz, fz}};

    const int rowA[4] = {wm * 64 + 0 * 16 + fr, wm * 64 + 1 * 16 + fr,
                         wm * 64 + 2 * 16 + fr, wm * 64 + 3 * 16 + fr};
    const int rowB[4] = {wn * 64 + 0 * 16 + fr, wn * 64 + 1 * 16 + fr,
                         wn * 64 + 2 * 16 + fr, wn * 64 + 3 * 16 + fr};
    int cA[4], cB[4];
    #pragma unroll
    for (int i = 0; i < 4; ++i) {
        cA[i] = (fq ^ ((rowA[i] >> 1) & 3)) * 8;
        cB[i] = (fq ^ ((rowB[i] >> 1) & 3)) * 8;
    }

    const int nk = K / 32;
    stage32(A, lda, m0, 0, smem, tid);                 // tile 0 -> buf 0
    stage32(Bm, ldb, n0, 0, smem + 4096, tid);
    stage32(A, lda, m0, 32, smem + 8192, tid);         // tile 1 -> buf 1
    stage32(Bm, ldb, n0, 32, smem + 8192 + 4096, tid);

    int cur = 0;
    for (int kt = 0; kt < nk; ++kt) {
        if (kt + 1 < nk) {
            asm volatile("s_waitcnt vmcnt(4)" ::: "memory");
        } else {
            asm volatile("s_waitcnt vmcnt(0)" ::: "memory");
        }
        __builtin_amdgcn_s_barrier();
        __builtin_amdgcn_sched_barrier(0);
        if (kt + 2 < nk) {
            int nxt = cur + 2; if (nxt >= 3) nxt -= 3;
            unsigned short* const An = smem + nxt * 8192;
            stage32(A, lda, m0, (kt + 2) * 32, An, tid);
            stage32(Bm, ldb, n0, (kt + 2) * 32, An + 4096, tid);
        }
        unsigned short* const As = smem + cur * 8192;
        unsigned short* const Bs = As + 4096;
        {
            bf16x8 af[4], bf[4];
            #pragma unroll
            for (int i = 0; i < 4; ++i)
                af[i] = *(const bf16x8*)&As[rowA[i] * 32 + cA[i]];
            #pragma unroll
            for (int j = 0; j < 4; ++j)
                bf[j] = *(const bf16x8*)&Bs[rowB[j] * 32 + cB[j]];
            #pragma unroll
            for (int i = 0; i < 4; ++i)
                #pragma unroll
                for (int j = 0; j < 4; ++j)
                    acc[i][j] = MFMA16(af[i], bf[j], acc[i][j]);
        }
        __builtin_amdgcn_sched_barrier(0);
        cur = (cur + 1 == 3) ? 0 : cur + 1;
    }

    __syncthreads();                           // loop reads done before Cs reuse
    auto Cs = (unsigned short(*)[128])smem;    // 32 KB of the 48 KB
    #pragma unroll
    for (int i = 0; i < 4; ++i)
        #pragma unroll
        for (int j = 0; j < 4; ++j) {
            const float bv = bias ? bias[n0 + wn * 64 + j * 16 + fr] : 0.f;
            #pragma unroll
            for (int r = 0; r < 4; ++r)
                Cs[wm * 64 + i * 16 + fq * 4 + r]
                  [(wn * 64 + j * 16 + fr) ^ (fq << 3)] =      // bank swizzle
                    f2bf(acc[i][j][r] + bv);
        }
    __syncthreads();
    const int r2 = tid >> 4, o2 = (tid & 15) * 8;
    #pragma unroll
    for (int i = 0; i < 8; ++i) {
        const int row = i * 16 + r2;
        const int o2s = o2 ^ (((row >> 2) & 3) << 3);          // undo swizzle
        *(uint4*)&C[(size_t)(m0 + row) * ldc + n0 + o2] = *(const uint4*)&Cs[row][o2s];
    }
}

// ---- merged dispatch: y==0 -> K-gen (bias), y==1 -> t-gemm -----------------
__global__ __launch_bounds__(256)
void gemm_pair(const unsigned short* __restrict__ A0, int lda0,
               const unsigned short* __restrict__ B0, int ldb0, int K0,
               unsigned short* __restrict__ C0, const float* __restrict__ bias0,
               const unsigned short* __restrict__ A1, int lda1,
               const unsigned short* __restrict__ B1, int ldb1, int K1,
               unsigned short* __restrict__ C1, int nN)
{
    if (blockIdx.y == 0)
        gemm_body(A0, lda0, B0, ldb0, K0, nN, C0, GL_, bias0);
    else
        gemm_body(A1, lda1, B1, ldb1, K1, nN, C1, GL_, nullptr);
}

// ---- k_y8: per block 8 edges; wave w computes y[e0+w] = t[e]@K[e]^T --------
__global__ __launch_bounds__(512)
void k_y8(unsigned short* tc, const unsigned short* __restrict__ Kc)
{
    const int e0 = blockIdx.x * 8;
    const int tid = threadIdx.x, lane = tid & 63, w = tid >> 6;
    const int e = e0 + w;
    const int fr = lane & 15, fq = lane >> 4;
    const unsigned short* A  = &tc[(size_t)e * GL_];
    const unsigned short* Bp = &Kc[(size_t)e * GL_];
    const f32x4 fz = {0.f, 0.f, 0.f, 0.f};
    f32x4 acc[4][4] = {{fz, fz, fz, fz}, {fz, fz, fz, fz},
                       {fz, fz, fz, fz}, {fz, fz, fz, fz}};
    #pragma unroll
    for (int ks = 0; ks < 2; ++ks) {
        bf16x8 af[4], bf[4];
        #pragma unroll
        for (int i = 0; i < 4; ++i)
            af[i] = *(const bf16x8*)&A[(i * 16 + fr) * 64 + ks * 32 + fq * 8];
        #pragma unroll
        for (int j = 0; j < 4; ++j)
            bf[j] = *(const bf16x8*)&Bp[(j * 16 + fr) * 64 + ks * 32 + fq * 8];
        #pragma unroll
        for (int i = 0; i < 4; ++i)
            #pragma unroll
            for (int j = 0; j < 4; ++j)
                acc[i][j] = MFMA16(af[i], bf[j], acc[i][j]);
    }
    __shared__ unsigned short y8[GL_ * 8];   // 64KB, [bg][8]
    #pragma unroll
    for (int i = 0; i < 4; ++i)
        #pragma unroll
        for (int j = 0; j < 4; ++j)
            #pragma unroll
            for (int r = 0; r < 4; ++r) {
                const int bg = (i * 16 + fq * 4 + r) * 64 + j * 16 + fr;
                y8[bg * 8 + w] = f2bf(acc[i][j][r]);
            }
    __syncthreads();
    unsigned short* dst = tc + (size_t)e0 * GL_;
    #pragma unroll
    for (int p = 0; p < 8; ++p) {
        const int o = (p * 512 + tid) * 8;
        *(uint4*)&dst[o] = *(const uint4*)&y8[o];
    }
}

// ---- k_accd: planes[pbase+ky] = incB8 @ y8^T, 64x128 tiles, direct loads ---
__global__ __launch_bounds__(256)
void k_accd(const unsigned short* __restrict__ Ae,   // incB8 + e_off*NP_
            const unsigned short* __restrict__ y8,   // chunk tc base
            unsigned short* __restrict__ planesB, int pbase, int K)
{
    const int xcd = blockIdx.x & 7, grp = blockIdx.x >> 3;   // grp 0..31
    const int m0 = (grp & 7) * 64;
    const int n0 = (xcd + 8 * (grp >> 3)) * 128;
    const int KSY = gridDim.y;
    const int kl = ((K / KSY) / 64) * 64;
    const int kbeg = blockIdx.y * kl;
    const int kend = ((int)blockIdx.y == KSY - 1) ? K : kbeg + kl;

    const int lane = threadIdx.x & 63, wid = threadIdx.x >> 6;
    const int wm = wid >> 1, wn = wid & 1;
    const int fr = lane & 15, fq = lane >> 4;

    const f32x4 fz = {0.f, 0.f, 0.f, 0.f};
    f32x4 acc[2][4] = {{fz, fz, fz, fz}, {fz, fz, fz, fz}};

    for (int kk = kbeg; kk < kend; kk += 64) {
        #pragma unroll
        for (int ks = 0; ks < 2; ++ks) {
            const int e8 = kk + ks * 32 + fq * 8;
            const size_t eb = (size_t)(e8 >> 3);
            bf16x8 af[2], bf[4];
            #pragma unroll
            for (int i = 0; i < 2; ++i)
                af[i] = *(const bf16x8*)&Ae[(eb * NP_ + m0 + wm * 32 + i * 16 + fr) * 8];
            #pragma unroll
            for (int j = 0; j < 4; ++j)
                bf[j] = *(const bf16x8*)&y8[eb * GL_ * 8 + (n0 + wn * 64 + j * 16 + fr) * 8];
            #pragma unroll
            for (int i = 0; i < 2; ++i)
                #pragma unroll
                for (int j = 0; j < 4; ++j)
                    acc[i][j] = MFMA16(af[i], bf[j], acc[i][j]);
        }
    }

    unsigned short* pl = planesB + (size_t)(pbase + blockIdx.y) * ACC_ELEMS;
    #pragma unroll
    for (int i = 0; i < 2; ++i)
        #pragma unroll
        for (int j = 0; j < 4; ++j) {
            const int col = n0 + wn * 64 + j * 16 + fr;
            const int b = col >> 6, g = col & 63;
            #pragma unroll
            for (int r = 0; r < 4; ++r) {
                const int n = m0 + wm * 32 + i * 16 + fq * 4 + r;
                if (n < N_)
                    pl[((size_t)b * N_ + n) * G_ + g] = f2bf(acc[i][j][r]);
            }
        }
}

// ======================= merged prologue (1 dispatch) =======================
constexpr int PREP_CVT = 2000, PREP_XT = 2512, PREP_W2 = 2640, PREP_NB = 10640;

__global__ __launch_bounds__(256)
void k_prep(const float* __restrict__ x, const float* __restrict__ inc,
            const float* __restrict__ ef, const float* __restrict__ W1,
            const float* __restrict__ b1, const float* __restrict__ W2,
            unsigned short* __restrict__ incT, unsigned short* __restrict__ incB8,
            unsigned short* __restrict__ xT, unsigned short* __restrict__ W2T,
            unsigned short* __restrict__ h)
{
    __shared__ __align__(16) char smraw[64 * 65 * 4];
    const int q = blockIdx.x;
    const int tid = threadIdx.x;

    if (q < PREP_CVT) {
        auto sm = (unsigned short(*)[80])smraw;
        const int e0 = (q % 250) * 64, n0 = (q / 250) * 64;
        const int cl = tid & 63;
        for (int rr = tid >> 6; rr < 64; rr += 4) {
            const int n = n0 + rr;
            sm[cl][rr] = (n < N_) ? f2bf(inc[(size_t)n * E_ + e0 + cl]) : (unsigned short)0;
        }
        __syncthreads();
        {
            const int cw = tid >> 2, j0 = (tid & 3) * 16;
            *(ushort8*)&incT[(size_t)(e0 + cw) * NP_ + n0 + j0]     = *(const ushort8*)&sm[cw][j0];
            *(ushort8*)&incT[(size_t)(e0 + cw) * NP_ + n0 + j0 + 8] = *(const ushort8*)&sm[cw][j0 + 8];
        }
        {
            const int eb = tid >> 5, idx = tid & 31;
            #pragma unroll
            for (int k = 0; k < 2; ++k) {
                const int row = idx * 2 + k;
                unsigned short tmp[8];
                #pragma unroll
                for (int p = 0; p < 8; ++p) tmp[p] = sm[eb * 8 + p][row];
                *(ushort8*)&incB8[((size_t)((e0 >> 3) + eb) * NP_ + n0 + row) * 8] =
                    *(const ushort8*)&tmp[0];
            }
        }
    } else if (q < PREP_W2) {
        auto sm = (float(*)[65])smraw;
        const float* in; unsigned short* out;
        int R, C, Rp, c0, r0;
        if (q < PREP_XT) {
            const int t = q - PREP_CVT, z = t >> 3, by = t & 7;
            in = x + (size_t)z * N_ * L_; out = xT + (size_t)z * L_ * NP_;
            R = N_; C = L_; Rp = NP_; c0 = 0; r0 = by * 64;
        } else {
            const int t = q - PREP_XT;
            in = W2; out = W2T;
            R = H_; C = GL_; Rp = H_; c0 = (t & 63) * 64; r0 = (t >> 6) * 64;
        }
        const int cl = tid & 63;
        for (int rr = tid >> 6; rr < 64; rr += 4) {
            const int r = r0 + rr;
            sm[cl][rr] = (r < R) ? in[(size_t)r * C + c0 + cl] : 0.f;
        }
        __syncthreads();
        const int cw = tid >> 2, j0 = (tid & 3) * 16;
        unsigned short tmp[16];
        #pragma unroll
        for (int j = 0; j < 16; ++j) tmp[j] = f2bf(sm[cw][j0 + j]);
        *(ushort8*)&out[(size_t)(c0 + cw) * Rp + r0 + j0]     = *(ushort8*)&tmp[0];
        *(ushort8*)&out[(size_t)(c0 + cw) * Rp + r0 + j0 + 8] = *(ushort8*)&tmp[8];
    } else {
        const int idx = (q - PREP_W2) * 256 + tid;
        const int e = idx >> 7, hh = idx & 127;
        float v = b1[hh];
        const float* efp = &ef[(size_t)e * F_];
        #pragma unroll
        for (int f = 0; f < F_; ++f) v += efp[f] * W1[f * H_ + hh];
        h[idx] = f2bf(fmaxf(v, 0.f));
    }
}

// ---- final: out = relu(sum_p bf16 planes[p] + bgc), single d_out write -----
__global__ __launch_bounds__(256)
void k_final(const unsigned short* __restrict__ planesB, int P,
             const float* __restrict__ bgc, float* __restrict__ out)
{
    const int i = (blockIdx.x * 256 + threadIdx.x) * 8;
    if (i >= ACC_ELEMS) return;
    float s[8];
    #pragma unroll
    for (int j = 0; j < 8; ++j) s[j] = bgc[(i + j) & 63];
    for (int p = 0; p < P; ++p) {
        const ushort8 v = *(const ushort8*)&planesB[(size_t)p * ACC_ELEMS + i];
        #pragma unroll
        for (int j = 0; j < 8; ++j) s[j] += bf2f((unsigned short)v[j]);
    }
    float4 o0, o1;
    o0.x = fmaxf(s[0], 0.f); o0.y = fmaxf(s[1], 0.f);
    o0.z = fmaxf(s[2], 0.f); o0.w = fmaxf(s[3], 0.f);
    o1.x = fmaxf(s[4], 0.f); o1.y = fmaxf(s[5], 0.f);
    o1.z = fmaxf(s[6], 0.f); o1.w = fmaxf(s[7], 0.f);
    *(float4*)&out[i]     = o0;
    *(float4*)&out[i + 4] = o1;
}

extern "C" void kernel_launch(void* const* d_in, const int* in_sizes, int n_in,
                              void* d_out, int out_size, void* d_ws, size_t ws_size,
                              hipStream_t stream) {
    const float* x   = (const float*)d_in[0];
    const float* inc = (const float*)d_in[1];
    const float* ef  = (const float*)d_in[2];
    const float* W1  = (const float*)d_in[3];
    const float* b1  = (const float*)d_in[4];
    const float* W2  = (const float*)d_in[5];
    const float* b2  = (const float*)d_in[6];
    const float* bgc = (const float*)d_in[7];
    float* out = (float*)d_out;

    const size_t persistU16 = (size_t)NP_ * E_      // incB8
                            + (size_t)E_ * NP_      // incT
                            + (size_t)B_ * L_ * NP_ // xT
                            + (size_t)E_ * H_       // h
                            + (size_t)GL_ * H_;     // W2T
    const size_t persistBytes = persistU16 * 2;     // ~41.9 MB

    // joint (nc, KS) search: prefer fewer chunks; for given nc prefer more
    // K-split planes (k_accd occupancy). Falls back to last round's (4,4).
    int nc = 16, KSv = 2, Ec = 1024;
    bool found = false;
    for (int c = 1; c <= 16 && !found; ++c) {
        for (int ks = 4; ks >= 2; --ks) {
            const int EcTry = ((E_ + c - 1) / c + 127) / 128 * 128;
            const size_t need = persistBytes
                              + (size_t)c * ks * ACC_ELEMS * 2   // bf16 planes
                              + 2 * (size_t)EcTry * GL_ * 2;     // K + t chunk
            if (need <= ws_size) { nc = c; KSv = ks; Ec = EcTry; found = true; break; }
        }
    }

    unsigned short* planesB = (unsigned short*)d_ws;
    unsigned short* incB8 = planesB + (size_t)nc * KSv * ACC_ELEMS;
    unsigned short* incT = incB8 + (size_t)NP_ * E_;
    unsigned short* xT   = incT + (size_t)E_ * NP_;
    unsigned short* h    = xT   + (size_t)B_ * L_ * NP_;
    unsigned short* W2T  = h    + (size_t)E_ * H_;
    unsigned short* Kc   = W2T  + (size_t)GL_ * H_;    // [Ec][4096]
    unsigned short* tc   = Kc   + (size_t)Ec * GL_;    // [Ec][4096]; later y8

    k_prep<<<dim3(PREP_NB), 256, 0, stream>>>(x, inc, ef, W1, b1, W2,
                                              incT, incB8, xT, W2T, h);

    int cidx = 0;
    for (int e_off = 0; e_off < E_; e_off += Ec, ++cidx) {
        const int ec = (E_ - e_off) < Ec ? (E_ - e_off) : Ec;   // multiple of 128
        gemm_pair<<<dim3((ec / 128) * 32, 2), 256, 0, stream>>>(
            h + (size_t)e_off * H_, H_, W2T, H_, H_, Kc, b2,
            incT + (size_t)e_off * NP_, NP_, xT, NP_, NP_, tc, 32);
        k_y8<<<dim3(ec / 8), 512, 0, stream>>>(tc, Kc);             // y8 over t
        k_accd<<<dim3(256, KSv), 256, 0, stream>>>(
            incB8 + (size_t)e_off * NP_, tc, planesB, cidx * KSv, ec);
    }

    k_final<<<dim3(ACC_ELEMS / 2048), 256, 0, stream>>>(planesB, nc * KSv, bgc, out);
}